// Round 6
// baseline (145.044 us; speedup 1.0000x reference)
//
#include <hip/hip_runtime.h>
#include <math.h>

#define N_NODES 50000
#define N_EDGES 800000
#define TGT     (N_NODES - 1)
#define C2MAX   256            // cap on in-degree of TGT (E[deg]=16)
#define KCAP    258            // max unique layer-1 dst nodes
#define ELMAX   256            // per-dst layer-1 edge cap
#define ROWS    (ELMAX + 1)
#define PBLK    8              // y-grid of fused kernel
#define SCANBLK 1024
#define BMWORDS 1568           // ceil(50000/32)=1563, rounded

// ---------------- workspace carve ----------------
struct WS {
  int* cnt;      // [16]  cnt[0]=#edges into TGT, cnt[1]=global fin   (memset 0)
  int* cnt2;     // [272] per-dst-slot edge counters                  (memset 0)
  int* fin_k;    // [272] per-dst completion counters                 (memset 0)
  int* e2src;    // [C2MAX]
  int* g_uniq;   // [272]
  int* g_slot;   // [C2MAX]
  int* g_misc;   // [16]  [0]=K1, [1]=kd
  int* l1src;    // [KCAP*ELMAX]
  float* W1T4;   // [65536]  layout: ((c>>2)*256 + o)*4 + (c&3)
  float* W2T4;   // [65536]
  float* g_xw2;  // [KCAP*256]
  float* g_as2;  // [KCAP*8]
  float* g_ad2;  // [KCAP*8]
  float* g_as1;  // [KCAP*ROWS*8]
  float* g_ad1;  // [KCAP*ROWS*8]
  float* g_xw1;  // [KCAP*ROWS*256]
};
__host__ __device__ inline WS carve(char* ws) {
  WS w; int* p = (int*)ws;
  w.cnt = p;    p += 16;
  w.cnt2 = p;   p += 272;
  w.fin_k = p;  p += 272;
  w.e2src = p;  p += C2MAX;
  w.g_uniq = p; p += 272;
  w.g_slot = p; p += C2MAX;
  w.g_misc = p; p += 16;
  w.l1src = p;  p += KCAP * ELMAX;
  float* f = (float*)p;
  w.W1T4 = f;   f += 65536;
  w.W2T4 = f;   f += 65536;
  w.g_xw2 = f;  f += KCAP * 256;
  w.g_as2 = f;  f += KCAP * 8;
  w.g_ad2 = f;  f += KCAP * 8;
  w.g_as1 = f;  f += KCAP * ROWS * 8;
  w.g_ad1 = f;  f += KCAP * ROWS * 8;
  w.g_xw1 = f;
  return w;
}

// ---- K1: LDS-tiled transpose of W1/W2 into float4-group layout; TGT edge scan
__global__ __launch_bounds__(256) void k_scan2(const int* __restrict__ eidx,
    const float* __restrict__ W1, const float* __restrict__ W2, char* ws) {
  WS w = carve(ws);
  int t = threadIdx.x;
  __shared__ float lds[64][65];
  if (blockIdx.x < 32) {                       // 2 matrices x 16 tiles of 64x64
    int m  = blockIdx.x >> 4;
    int ti = (blockIdx.x >> 2) & 3, tj = blockIdx.x & 3;
    const float* src = m ? W2 : W1;
    float*       dst = m ? w.W2T4 : w.W1T4;
    int r0 = t >> 6, cc = t & 63;
    for (int p = 0; p < 16; ++p) {             // coalesced reads
      int r = p * 4 + r0;
      lds[r][cc] = src[(ti * 64 + r) * 256 + tj * 64 + cc];
    }
    __syncthreads();
    int c40 = t >> 6, o = t & 63;
    for (int p2 = 0; p2 < 4; ++p2) {           // coalesced float4 writes
      int c4l = p2 * 4 + c40;
      float4 v = make_float4(lds[o][4 * c4l + 0], lds[o][4 * c4l + 1],
                             lds[o][4 * c4l + 2], lds[o][4 * c4l + 3]);
      ((float4*)dst)[(tj * 16 + c4l) * 256 + ti * 64 + o] = v;
    }
  }
  int tid = blockIdx.x * 256 + t;
  int nthreads = gridDim.x * 256;
  const int* esrc = eidx;
  const int4* edst4 = (const int4*)(eidx + N_EDGES);
  for (int i = tid; i < N_EDGES / 4; i += nthreads) {
    int4 d = edst4[i];
    int dv[4] = {d.x, d.y, d.z, d.w};
#pragma unroll
    for (int j = 0; j < 4; ++j)
      if (dv[j] == TGT) {
        int p = atomicAdd(&w.cnt[0], 1);
        if (p < C2MAX) w.e2src[p] = esrc[4 * i + j];
      }
  }
}

// ---- K2: per-block dedup + LDS bitmap membership; bucket edges per dst ----
__global__ __launch_bounds__(256) void k_scan1(const int* __restrict__ eidx, char* ws) {
  WS w = carve(ws);
  int t = threadIdx.x;
  __shared__ int s_e[C2MAX], s_scan[256], s_uniq[KCAP], s_slot[C2MAX], s_kv[2];
  __shared__ unsigned s_bm[BMWORDS];
  int c2 = min(w.cnt[0], C2MAX);
  // dedup: first-occurrence ranks via prefix sum (identical in every block)
  if (t < c2) s_e[t] = w.e2src[t];
  __syncthreads();
  int firstIdx = t;
  if (t < c2) {
    int s = s_e[t];
    for (int q = 0; q < t; ++q) if (s_e[q] == s) { firstIdx = q; break; }
  }
  s_scan[t] = (t < c2 && firstIdx == t) ? 1 : 0;
  __syncthreads();
  for (int off = 1; off < 256; off <<= 1) {
    int add = (t >= off) ? s_scan[t - off] : 0;
    __syncthreads();
    s_scan[t] += add;
    __syncthreads();
  }
  if (t < c2 && firstIdx == t) s_uniq[s_scan[t] - 1] = s_e[t];
  __syncthreads();
  if (t < c2) s_slot[t] = s_scan[firstIdx] - 1;
  if (t == 0) {
    int K1 = (c2 > 0) ? s_scan[255] : 0;
    int kd = -1;
    for (int i = 0; i < K1; ++i) if (s_uniq[i] == TGT) { kd = i; break; }
    if (kd < 0) { s_uniq[K1] = TGT; kd = K1; K1++; }
    s_kv[0] = K1; s_kv[1] = kd;
  }
  for (int i = t; i < BMWORDS; i += 256) s_bm[i] = 0u;
  __syncthreads();
  int K1 = s_kv[0];
  for (int i = t; i < K1; i += 256) {
    int u = s_uniq[i];
    atomicOr(&s_bm[u >> 5], 1u << (u & 31));
  }
  if (blockIdx.x == 0) {
    for (int i = t; i < K1; i += 256) w.g_uniq[i] = s_uniq[i];
    if (t < c2) w.g_slot[t] = s_slot[t];
    if (t == 0) { w.g_misc[0] = K1; w.g_misc[1] = s_kv[1]; }
  }
  __syncthreads();
  int tid = blockIdx.x * 256 + t;
  int nthreads = gridDim.x * 256;
  const int* esrc = eidx;
  const int4* edst4 = (const int4*)(eidx + N_EDGES);
  for (int i = tid; i < N_EDGES / 4; i += nthreads) {
    int4 d = edst4[i];
    int dv[4] = {d.x, d.y, d.z, d.w};
#pragma unroll
    for (int j = 0; j < 4; ++j) {
      int u = dv[j];
      if ((s_bm[u >> 5] >> (u & 31)) & 1u) {   // exact: bit index == node id
        int k = 0;
        for (int q = 0; q < K1; ++q) if (s_uniq[q] == u) { k = q; break; }
        int p = atomicAdd(&w.cnt2[k], 1);
        if (p < ELMAX) w.l1src[k * ELMAX + p] = esrc[4 * i + j];
      }
    }
  }
}

// ---- K3 (fused): xw1 batches -> [last y-block] attn+GELU+xw2 -> [last dst] final
__global__ __launch_bounds__(256) void k_fused(const float* __restrict__ x,
    const float* __restrict__ aS1, const float* __restrict__ aD1,
    const float* __restrict__ b1, const float* __restrict__ aS2,
    const float* __restrict__ aD2, const float* __restrict__ b2,
    float* __restrict__ out, char* ws) {
  WS w = carve(ws);
  int K1 = w.g_misc[0];
  int k = blockIdx.x;
  if (k >= K1) return;
  int t = threadIdx.x;
  int ne = min(w.cnt2[k], ELMAX);
  int items = ne + 1;                          // edges + the dst node itself
  int myNode = w.g_uniq[k];
  __shared__ __align__(16) float s_xsT[4 * 256];
  __shared__ float s_redS[4 * 256], s_redD[4 * 256];
  __shared__ float s_as[ROWS * 8];
  __shared__ float s_p[ELMAX * 8];
  __shared__ float s_den[8];
  __shared__ __align__(16) float s_h1[256];
  __shared__ int   s_sl[C2MAX];
  __shared__ int   s_win;
  const float4* W1v = (const float4*)w.W1T4;
  const float4* W2v = (const float4*)w.W2T4;
  const float4* xsT4 = (const float4*)s_xsT;

  // ---- phase 1: xw1 + attention dots for my batches ----
  for (int b = blockIdx.y; b * 4 < items; b += PBLK) {
    int base = b * 4;
    int na = min(4, items - base);
    for (int i = 0; i < na; ++i) {
      int it = base + i;
      int node = (it < ne) ? w.l1src[k * ELMAX + it] : myNode;
      s_xsT[t * 4 + i] = x[(size_t)node * 256 + t];
    }
    __syncthreads();
    float a0 = 0.f, a1 = 0.f, a2 = 0.f, a3 = 0.f;
#pragma unroll 8
    for (int c4 = 0; c4 < 64; ++c4) {
      float4 wv = W1v[c4 * 256 + t];           // 16 B/lane, coalesced
      float4 x0 = xsT4[4 * c4 + 0];            // items for channel 4c4+0 (broadcast)
      float4 x1 = xsT4[4 * c4 + 1];
      float4 x2 = xsT4[4 * c4 + 2];
      float4 x3 = xsT4[4 * c4 + 3];
      a0 = fmaf(wv.x, x0.x, a0); a0 = fmaf(wv.y, x1.x, a0); a0 = fmaf(wv.z, x2.x, a0); a0 = fmaf(wv.w, x3.x, a0);
      a1 = fmaf(wv.x, x0.y, a1); a1 = fmaf(wv.y, x1.y, a1); a1 = fmaf(wv.z, x2.y, a1); a1 = fmaf(wv.w, x3.y, a1);
      a2 = fmaf(wv.x, x0.z, a2); a2 = fmaf(wv.y, x1.z, a2); a2 = fmaf(wv.z, x2.z, a2); a2 = fmaf(wv.w, x3.z, a2);
      a3 = fmaf(wv.x, x0.w, a3); a3 = fmaf(wv.y, x1.w, a3); a3 = fmaf(wv.z, x2.w, a3); a3 = fmaf(wv.w, x3.w, a3);
    }
    float accs[4] = {a0, a1, a2, a3};
    for (int i = 0; i < na; ++i) {
      int row = k * ROWS + base + i;
      w.g_xw1[(size_t)row * 256 + t] = accs[i];
      s_redS[i * 256 + t] = accs[i] * aS1[t];
      s_redD[i * 256 + t] = accs[i] * aD1[t];
    }
    __syncthreads();
    if (t < 32) {
      int i = t >> 3, h = t & 7;
      if (i < na) {
        float s = 0.f, dd = 0.f;
        for (int q = 0; q < 32; ++q) {
          s  += s_redS[i * 256 + h * 32 + q];
          dd += s_redD[i * 256 + h * 32 + q];
        }
        int row = k * ROWS + base + i;
        w.g_as1[row * 8 + h] = s;
        w.g_ad1[row * 8 + h] = dd;
      }
    }
    __syncthreads();
  }

  // ---- per-dst join: PBLK-th y-block proceeds to attention ----
  __syncthreads();
  if (t == 0) {
    __threadfence();
    int old = __hip_atomic_fetch_add(&w.fin_k[k], 1, __ATOMIC_ACQ_REL, __HIP_MEMORY_SCOPE_AGENT);
    s_win = (old == PBLK - 1);
  }
  __syncthreads();
  if (!s_win) return;
  __threadfence();

  // ---- phase 2: softmax + aggregate + bias + exact GELU + xw2 ----
  for (int i = t; i < items * 8; i += 256) s_as[i] = w.g_as1[(size_t)(k * ROWS) * 8 + i];
  __syncthreads();
  if (t < 8) {
    int h = t;
    float adst = s_as[ne * 8 + h];             // a_dst of the dst node (item ne)... 
    adst = w.g_ad1[(size_t)(k * ROWS + ne) * 8 + h];
    float m = -INFINITY;
    for (int j = 0; j < ne; ++j) {
      float e = s_as[j * 8 + h] + adst;
      e = (e >= 0.f) ? e : 0.2f * e;
      m = fmaxf(m, e);
    }
    float den = 0.f;
    for (int j = 0; j < ne; ++j) {
      float e = s_as[j * 8 + h] + adst;
      e = (e >= 0.f) ? e : 0.2f * e;
      float p = expf(e - m);
      s_p[j * 8 + h] = p;
      den += p;
    }
    s_den[h] = den + 1e-16f;
  }
  __syncthreads();
  int h = t >> 5;
  float acc = 0.f;
  const float* xwb = w.g_xw1 + (size_t)(k * ROWS) * 256 + t;
#pragma unroll 4
  for (int j = 0; j < ne; ++j)
    acc = fmaf(s_p[j * 8 + h], xwb[(size_t)j * 256], acc);
  float o = (ne > 0) ? acc / s_den[h] : 0.f;
  o += b1[t];
  s_h1[t] = 0.5f * o * (1.f + erff(o * 0.70710678118654752440f));  // exact GELU
  __syncthreads();
  float a2s = 0.f;
  const float4* h1v = (const float4*)s_h1;
#pragma unroll 8
  for (int c4 = 0; c4 < 64; ++c4) {
    float4 wv = W2v[c4 * 256 + t];
    float4 hv = h1v[c4];
    a2s = fmaf(wv.x, hv.x, a2s); a2s = fmaf(wv.y, hv.y, a2s);
    a2s = fmaf(wv.z, hv.z, a2s); a2s = fmaf(wv.w, hv.w, a2s);
  }
  w.g_xw2[k * 256 + t] = a2s;
  s_redS[t] = a2s * aS2[t];
  s_redD[t] = a2s * aD2[t];
  __syncthreads();
  if (t < 8) {
    float s = 0.f, dd = 0.f;
    for (int q = 0; q < 32; ++q) { s += s_redS[t * 32 + q]; dd += s_redD[t * 32 + q]; }
    w.g_as2[k * 8 + t] = s;
    w.g_ad2[k * 8 + t] = dd;
  }

  // ---- global join: K1-th finishing dst runs layer-2 attention for TGT ----
  __syncthreads();
  if (t == 0) {
    __threadfence();
    int old = __hip_atomic_fetch_add(&w.cnt[1], 1, __ATOMIC_ACQ_REL, __HIP_MEMORY_SCOPE_AGENT);
    s_win = (old == K1 - 1);
  }
  __syncthreads();
  if (!s_win) return;
  __threadfence();

  // ---- phase 3: layer-2 attention for node TGT ----
  int c2 = min(w.cnt[0], C2MAX);
  int kd = w.g_misc[1];
  for (int j = t; j < c2; j += 256) s_sl[j] = w.g_slot[j];
  __syncthreads();
  if (t < 8) {
    float adst = w.g_ad2[kd * 8 + t];
    float m = -INFINITY;
    for (int j = 0; j < c2; ++j) {
      float e = w.g_as2[s_sl[j] * 8 + t] + adst;
      e = (e >= 0.f) ? e : 0.2f * e;
      m = fmaxf(m, e);
    }
    float den = 0.f;
    for (int j = 0; j < c2; ++j) {
      float e = w.g_as2[s_sl[j] * 8 + t] + adst;
      e = (e >= 0.f) ? e : 0.2f * e;
      float p = expf(e - m);
      s_p[j * 8 + t] = p;
      den += p;
    }
    s_den[t] = den + 1e-16f;
  }
  __syncthreads();
  float acc2 = 0.f;
  for (int j = 0; j < c2; ++j)
    acc2 = fmaf(s_p[j * 8 + h], w.g_xw2[s_sl[j] * 256 + t], acc2);
  float o2 = (c2 > 0) ? acc2 / s_den[h] : 0.f;
  out[t] = o2 + b2[t];
}

extern "C" void kernel_launch(void* const* d_in, const int* in_sizes, int n_in,
                              void* d_out, int out_size, void* d_ws, size_t ws_size,
                              hipStream_t stream) {
  const float* x    = (const float*)d_in[0];
  const int*   eidx = (const int*)d_in[1];
  const float* W1   = (const float*)d_in[2];
  const float* aS1  = (const float*)d_in[3];
  const float* aD1  = (const float*)d_in[4];
  const float* b1   = (const float*)d_in[5];
  const float* W2   = (const float*)d_in[6];
  const float* aS2  = (const float*)d_in[7];
  const float* aD2  = (const float*)d_in[8];
  const float* b2   = (const float*)d_in[9];
  float* out = (float*)d_out;
  char*  ws  = (char*)d_ws;

  hipMemsetAsync(ws, 0, (16 + 272 + 272) * sizeof(int), stream);  // cnt+cnt2+fin_k

  k_scan2<<<SCANBLK, 256, 0, stream>>>(eidx, W1, W2, ws);
  k_scan1<<<SCANBLK, 256, 0, stream>>>(eidx, ws);
  k_fused<<<dim3(KCAP, PBLK), 256, 0, stream>>>(x, aS1, aD1, b1, aS2, aD2, b2, out, ws);
}

// Round 7
// 137.772 us; speedup vs baseline: 1.0528x; 1.0528x over previous
//
#include <hip/hip_runtime.h>
#include <math.h>

#define N_NODES 50000
#define N_EDGES 800000
#define TGT     (N_NODES - 1)
#define C2MAX   256            // cap on in-degree of TGT (E[deg]=16)
#define KCAP    258            // max unique layer-1 dst nodes
#define ELMAX   256            // per-dst layer-1 edge cap
#define ROWS    (ELMAX + 1)
#define PBLK    8              // y-grid of fused kernel
#define SCANBLK 1024
#define BMWORDS 1568           // ceil(50000/32)=1563, rounded

// ---------------- workspace carve ----------------
struct WS {
  int* cnt;      // [16]  cnt[0]=#edges into TGT, cnt[1]=global fin   (memset 0)
  int* cnt2;     // [272] per-dst-slot edge counters                  (memset 0)
  int* fin_k;    // [272] per-dst completion counters                 (memset 0)
  int* e2src;    // [C2MAX]
  int* g_uniq;   // [272]
  int* g_slot;   // [C2MAX]
  int* g_misc;   // [16]  [0]=K1, [1]=kd
  int* l1src;    // [KCAP*ELMAX]
  float* W1T4;   // [65536]  layout: ((c>>2)*256 + o)*4 + (c&3)
  float* W2T4;   // [65536]
  float* g_xw2;  // [KCAP*256]
  float* g_as2;  // [KCAP*8]
  float* g_ad2;  // [KCAP*8]
  float* g_as1;  // [KCAP*ROWS*8]
  float* g_ad1;  // [KCAP*ROWS*8]
  float* g_xw1;  // [KCAP*ROWS*256]
};
__host__ __device__ inline WS carve(char* ws) {
  WS w; int* p = (int*)ws;
  w.cnt = p;    p += 16;
  w.cnt2 = p;   p += 272;
  w.fin_k = p;  p += 272;
  w.e2src = p;  p += C2MAX;
  w.g_uniq = p; p += 272;
  w.g_slot = p; p += C2MAX;
  w.g_misc = p; p += 16;
  w.l1src = p;  p += KCAP * ELMAX;
  float* f = (float*)p;
  w.W1T4 = f;   f += 65536;
  w.W2T4 = f;   f += 65536;
  w.g_xw2 = f;  f += KCAP * 256;
  w.g_as2 = f;  f += KCAP * 8;
  w.g_ad2 = f;  f += KCAP * 8;
  w.g_as1 = f;  f += KCAP * ROWS * 8;
  w.g_ad1 = f;  f += KCAP * ROWS * 8;
  w.g_xw1 = f;
  return w;
}

// ---- K1: LDS-tiled transpose of W1/W2 into float4-group layout; TGT edge scan
__global__ __launch_bounds__(256) void k_scan2(const int* __restrict__ eidx,
    const float* __restrict__ W1, const float* __restrict__ W2, char* ws) {
  WS w = carve(ws);
  int t = threadIdx.x;
  __shared__ float lds[64][65];
  if (blockIdx.x < 32) {                       // 2 matrices x 16 tiles of 64x64
    int m  = blockIdx.x >> 4;
    int ti = (blockIdx.x >> 2) & 3, tj = blockIdx.x & 3;
    const float* src = m ? W2 : W1;
    float*       dst = m ? w.W2T4 : w.W1T4;
    int r0 = t >> 6, cc = t & 63;
    float tmp[16];
#pragma unroll
    for (int p = 0; p < 16; ++p)               // 16 independent coalesced loads
      tmp[p] = src[(ti * 64 + p * 4 + r0) * 256 + tj * 64 + cc];
#pragma unroll
    for (int p = 0; p < 16; ++p)
      lds[p * 4 + r0][cc] = tmp[p];
    __syncthreads();
    int c40 = t >> 6, o = t & 63;
#pragma unroll
    for (int p2 = 0; p2 < 4; ++p2) {           // coalesced float4 writes
      int c4l = p2 * 4 + c40;
      float4 v = make_float4(lds[o][4 * c4l + 0], lds[o][4 * c4l + 1],
                             lds[o][4 * c4l + 2], lds[o][4 * c4l + 3]);
      ((float4*)dst)[(tj * 16 + c4l) * 256 + ti * 64 + o] = v;
    }
  }
  int tid = blockIdx.x * 256 + t;
  int nthreads = gridDim.x * 256;
  const int* esrc = eidx;
  const int4* edst4 = (const int4*)(eidx + N_EDGES);
  for (int i = tid; i < N_EDGES / 4; i += nthreads) {
    int4 d = edst4[i];
    int dv[4] = {d.x, d.y, d.z, d.w};
#pragma unroll
    for (int j = 0; j < 4; ++j)
      if (dv[j] == TGT) {
        int p = atomicAdd(&w.cnt[0], 1);
        if (p < C2MAX) w.e2src[p] = esrc[4 * i + j];
      }
  }
}

// ---- K2: per-block dedup + LDS bitmap membership; bucket edges per dst ----
__global__ __launch_bounds__(256) void k_scan1(const int* __restrict__ eidx, char* ws) {
  WS w = carve(ws);
  int t = threadIdx.x;
  __shared__ int s_e[C2MAX], s_scan[256], s_uniq[KCAP], s_slot[C2MAX], s_kv[2];
  __shared__ unsigned s_bm[BMWORDS];
  int c2 = min(w.cnt[0], C2MAX);
  if (t < c2) s_e[t] = w.e2src[t];
  __syncthreads();
  int firstIdx = t;
  if (t < c2) {
    int s = s_e[t];
    for (int q = 0; q < t; ++q) if (s_e[q] == s) { firstIdx = q; break; }
  }
  s_scan[t] = (t < c2 && firstIdx == t) ? 1 : 0;
  __syncthreads();
  for (int off = 1; off < 256; off <<= 1) {
    int add = (t >= off) ? s_scan[t - off] : 0;
    __syncthreads();
    s_scan[t] += add;
    __syncthreads();
  }
  if (t < c2 && firstIdx == t) s_uniq[s_scan[t] - 1] = s_e[t];
  __syncthreads();
  if (t < c2) s_slot[t] = s_scan[firstIdx] - 1;
  if (t == 0) {
    int K1 = (c2 > 0) ? s_scan[255] : 0;
    int kd = -1;
    for (int i = 0; i < K1; ++i) if (s_uniq[i] == TGT) { kd = i; break; }
    if (kd < 0) { s_uniq[K1] = TGT; kd = K1; K1++; }
    s_kv[0] = K1; s_kv[1] = kd;
  }
  for (int i = t; i < BMWORDS; i += 256) s_bm[i] = 0u;
  __syncthreads();
  int K1 = s_kv[0];
  for (int i = t; i < K1; i += 256) {
    int u = s_uniq[i];
    atomicOr(&s_bm[u >> 5], 1u << (u & 31));
  }
  if (blockIdx.x == 0) {
    for (int i = t; i < K1; i += 256) w.g_uniq[i] = s_uniq[i];
    if (t < c2) w.g_slot[t] = s_slot[t];
    if (t == 0) { w.g_misc[0] = K1; w.g_misc[1] = s_kv[1]; }
  }
  __syncthreads();
  int tid = blockIdx.x * 256 + t;
  int nthreads = gridDim.x * 256;
  const int* esrc = eidx;
  const int4* edst4 = (const int4*)(eidx + N_EDGES);
  for (int i = tid; i < N_EDGES / 4; i += nthreads) {
    int4 d = edst4[i];
    int dv[4] = {d.x, d.y, d.z, d.w};
#pragma unroll
    for (int j = 0; j < 4; ++j) {
      int u = dv[j];
      if ((s_bm[u >> 5] >> (u & 31)) & 1u) {   // exact: bit index == node id
        int k = 0;
        for (int q = 0; q < K1; ++q) if (s_uniq[q] == u) { k = q; break; }
        int p = atomicAdd(&w.cnt2[k], 1);
        if (p < ELMAX) w.l1src[k * ELMAX + p] = esrc[4 * i + j];
      }
    }
  }
}

// ---- K3 (fused): xw1 batches -> [last y-block] attn+GELU+xw2 -> [last dst] final
__global__ __launch_bounds__(256) void k_fused(const float* __restrict__ x,
    const float* __restrict__ aS1, const float* __restrict__ aD1,
    const float* __restrict__ b1, const float* __restrict__ aS2,
    const float* __restrict__ aD2, const float* __restrict__ b2,
    float* __restrict__ out, char* ws) {
  WS w = carve(ws);
  int K1 = w.g_misc[0];
  int k = blockIdx.x;
  if (k >= K1) return;
  int t = threadIdx.x;
  int ne = min(w.cnt2[k], ELMAX);
  int items = ne + 1;                          // edges + the dst node itself
  int myNode = w.g_uniq[k];
  __shared__ __align__(16) float s_xsT[4 * 256];
  __shared__ float s_redS[4 * 256], s_redD[4 * 256];
  __shared__ float s_as[ROWS * 8];
  __shared__ float s_p[ELMAX * 8];
  __shared__ float s_den[8];
  __shared__ __align__(16) float s_h1[256];
  __shared__ int   s_sl[C2MAX];
  __shared__ int   s_win;
  const float4* W1v = (const float4*)w.W1T4;
  const float4* W2v = (const float4*)w.W2T4;
  const float4* xsT4 = (const float4*)s_xsT;

  // ---- phase 1: xw1 + attention dots for my batches ----
  for (int b = blockIdx.y; b * 4 < items; b += PBLK) {
    int base = b * 4;
    int na = min(4, items - base);
    int nd[4];
#pragma unroll
    for (int i = 0; i < 4; ++i) {              // 4 independent index loads
      int it = base + i;
      nd[i] = (it < ne) ? w.l1src[k * ELMAX + it] : myNode;
    }
#pragma unroll
    for (int i = 0; i < 4; ++i)                // 4 independent row loads in flight
      s_xsT[t * 4 + i] = x[(size_t)nd[i] * 256 + t];
    __syncthreads();
    float a0 = 0.f, a1 = 0.f, a2 = 0.f, a3 = 0.f;
    for (int cc = 0; cc < 64; cc += 8) {
      float4 wreg[8];
#pragma unroll
      for (int j = 0; j < 8; ++j)              // 8 W loads issued before any use
        wreg[j] = W1v[(size_t)(cc + j) * 256 + t];
#pragma unroll
      for (int j = 0; j < 8; ++j) {
        float4 wv = wreg[j];
        int c4 = cc + j;
        float4 x0 = xsT4[4 * c4 + 0];
        float4 x1 = xsT4[4 * c4 + 1];
        float4 x2 = xsT4[4 * c4 + 2];
        float4 x3 = xsT4[4 * c4 + 3];
        a0 = fmaf(wv.x, x0.x, a0); a0 = fmaf(wv.y, x1.x, a0); a0 = fmaf(wv.z, x2.x, a0); a0 = fmaf(wv.w, x3.x, a0);
        a1 = fmaf(wv.x, x0.y, a1); a1 = fmaf(wv.y, x1.y, a1); a1 = fmaf(wv.z, x2.y, a1); a1 = fmaf(wv.w, x3.y, a1);
        a2 = fmaf(wv.x, x0.z, a2); a2 = fmaf(wv.y, x1.z, a2); a2 = fmaf(wv.z, x2.z, a2); a2 = fmaf(wv.w, x3.z, a2);
        a3 = fmaf(wv.x, x0.w, a3); a3 = fmaf(wv.y, x1.w, a3); a3 = fmaf(wv.z, x2.w, a3); a3 = fmaf(wv.w, x3.w, a3);
      }
    }
    float accs[4] = {a0, a1, a2, a3};
    for (int i = 0; i < na; ++i) {
      int row = k * ROWS + base + i;
      w.g_xw1[(size_t)row * 256 + t] = accs[i];
      s_redS[i * 256 + t] = accs[i] * aS1[t];
      s_redD[i * 256 + t] = accs[i] * aD1[t];
    }
    __syncthreads();
    if (t < 32) {
      int i = t >> 3, h = t & 7;
      if (i < na) {
        float s = 0.f, dd = 0.f;
        for (int q = 0; q < 32; ++q) {
          s  += s_redS[i * 256 + h * 32 + q];
          dd += s_redD[i * 256 + h * 32 + q];
        }
        int row = k * ROWS + base + i;
        w.g_as1[row * 8 + h] = s;
        w.g_ad1[row * 8 + h] = dd;
      }
    }
    __syncthreads();
  }

  // ---- per-dst join: PBLK-th y-block proceeds to attention ----
  __syncthreads();
  if (t == 0) {
    __threadfence();
    int old = __hip_atomic_fetch_add(&w.fin_k[k], 1, __ATOMIC_ACQ_REL, __HIP_MEMORY_SCOPE_AGENT);
    s_win = (old == PBLK - 1);
  }
  __syncthreads();
  if (!s_win) return;
  __threadfence();

  // ---- phase 2: softmax + aggregate + bias + exact GELU + xw2 ----
  for (int i = t; i < items * 8; i += 256) s_as[i] = w.g_as1[(size_t)(k * ROWS) * 8 + i];
  __syncthreads();
  if (t < 8) {
    int h = t;
    float adst = w.g_ad1[(size_t)(k * ROWS + ne) * 8 + h];
    float m = -INFINITY;
    for (int j = 0; j < ne; ++j) {
      float e = s_as[j * 8 + h] + adst;
      e = (e >= 0.f) ? e : 0.2f * e;
      m = fmaxf(m, e);
    }
    float den = 0.f;
    for (int j = 0; j < ne; ++j) {
      float e = s_as[j * 8 + h] + adst;
      e = (e >= 0.f) ? e : 0.2f * e;
      float p = expf(e - m);
      s_p[j * 8 + h] = p;
      den += p;
    }
    s_den[h] = den + 1e-16f;
  }
  __syncthreads();
  int h = t >> 5;
  float acc = 0.f;
  const float* xwb = w.g_xw1 + (size_t)(k * ROWS) * 256 + t;
  for (int j0 = 0; j0 < ne; j0 += 8) {
    float tmp[8];
#pragma unroll
    for (int j = 0; j < 8; ++j)                // 8 gathers in flight
      tmp[j] = (j0 + j < ne) ? xwb[(size_t)(j0 + j) * 256] : 0.f;
#pragma unroll
    for (int j = 0; j < 8; ++j)
      if (j0 + j < ne) acc = fmaf(s_p[(j0 + j) * 8 + h], tmp[j], acc);
  }
  float o = (ne > 0) ? acc / s_den[h] : 0.f;
  o += b1[t];
  s_h1[t] = 0.5f * o * (1.f + erff(o * 0.70710678118654752440f));  // exact GELU
  __syncthreads();
  float a2s = 0.f;
  const float4* h1v = (const float4*)s_h1;
  for (int cc = 0; cc < 64; cc += 8) {
    float4 wreg[8];
#pragma unroll
    for (int j = 0; j < 8; ++j)
      wreg[j] = W2v[(size_t)(cc + j) * 256 + t];
#pragma unroll
    for (int j = 0; j < 8; ++j) {
      float4 wv = wreg[j];
      float4 hv = h1v[cc + j];
      a2s = fmaf(wv.x, hv.x, a2s); a2s = fmaf(wv.y, hv.y, a2s);
      a2s = fmaf(wv.z, hv.z, a2s); a2s = fmaf(wv.w, hv.w, a2s);
    }
  }
  w.g_xw2[k * 256 + t] = a2s;
  s_redS[t] = a2s * aS2[t];
  s_redD[t] = a2s * aD2[t];
  __syncthreads();
  if (t < 8) {
    float s = 0.f, dd = 0.f;
    for (int q = 0; q < 32; ++q) { s += s_redS[t * 32 + q]; dd += s_redD[t * 32 + q]; }
    w.g_as2[k * 8 + t] = s;
    w.g_ad2[k * 8 + t] = dd;
  }

  // ---- global join: K1-th finishing dst runs layer-2 attention for TGT ----
  __syncthreads();
  if (t == 0) {
    __threadfence();
    int old = __hip_atomic_fetch_add(&w.cnt[1], 1, __ATOMIC_ACQ_REL, __HIP_MEMORY_SCOPE_AGENT);
    s_win = (old == K1 - 1);
  }
  __syncthreads();
  if (!s_win) return;
  __threadfence();

  // ---- phase 3: layer-2 attention for node TGT ----
  int c2 = min(w.cnt[0], C2MAX);
  int kd = w.g_misc[1];
  for (int j = t; j < c2; j += 256) s_sl[j] = w.g_slot[j];
  __syncthreads();
  if (t < 8) {
    float adst = w.g_ad2[kd * 8 + t];
    float m = -INFINITY;
    for (int j = 0; j < c2; ++j) {
      float e = w.g_as2[s_sl[j] * 8 + t] + adst;
      e = (e >= 0.f) ? e : 0.2f * e;
      m = fmaxf(m, e);
    }
    float den = 0.f;
    for (int j = 0; j < c2; ++j) {
      float e = w.g_as2[s_sl[j] * 8 + t] + adst;
      e = (e >= 0.f) ? e : 0.2f * e;
      float p = expf(e - m);
      s_p[j * 8 + t] = p;
      den += p;
    }
    s_den[t] = den + 1e-16f;
  }
  __syncthreads();
  float acc2 = 0.f;
  for (int j0 = 0; j0 < c2; j0 += 8) {
    float tmp[8];
#pragma unroll
    for (int j = 0; j < 8; ++j)
      tmp[j] = (j0 + j < c2) ? w.g_xw2[s_sl[j0 + j] * 256 + t] : 0.f;
#pragma unroll
    for (int j = 0; j < 8; ++j)
      if (j0 + j < c2) acc2 = fmaf(s_p[(j0 + j) * 8 + h], tmp[j], acc2);
  }
  float o2 = (c2 > 0) ? acc2 / s_den[h] : 0.f;
  out[t] = o2 + b2[t];
}

extern "C" void kernel_launch(void* const* d_in, const int* in_sizes, int n_in,
                              void* d_out, int out_size, void* d_ws, size_t ws_size,
                              hipStream_t stream) {
  const float* x    = (const float*)d_in[0];
  const int*   eidx = (const int*)d_in[1];
  const float* W1   = (const float*)d_in[2];
  const float* aS1  = (const float*)d_in[3];
  const float* aD1  = (const float*)d_in[4];
  const float* b1   = (const float*)d_in[5];
  const float* W2   = (const float*)d_in[6];
  const float* aS2  = (const float*)d_in[7];
  const float* aD2  = (const float*)d_in[8];
  const float* b2   = (const float*)d_in[9];
  float* out = (float*)d_out;
  char*  ws  = (char*)d_ws;

  hipMemsetAsync(ws, 0, (16 + 272 + 272) * sizeof(int), stream);  // cnt+cnt2+fin_k

  k_scan2<<<SCANBLK, 256, 0, stream>>>(eidx, W1, W2, ws);
  k_scan1<<<SCANBLK, 256, 0, stream>>>(eidx, ws);
  k_fused<<<dim3(KCAP, PBLK), 256, 0, stream>>>(x, aS1, aD1, b1, aS2, aD2, b2, out, ws);
}